// Round 10
// baseline (438.143 us; speedup 1.0000x reference)
//
#include <hip/hip_runtime.h>
#include <hip/hip_cooperative_groups.h>

namespace cg = cooperative_groups;

#define PAD 64
#define NSLOT 64
#define NTHR 256

// shared-memory union: gemm needs 4096(Ws)+4096(xs)+128+128 floats = 8448
#define SM_FLOATS 8448

// ================= device phase functions (shared by mega + fallback) =================

__device__ void gemm_phase(const float* __restrict__ A, const float* __restrict__ W,
                           const float* __restrict__ bias, float* __restrict__ out,
                           int n, float invN,
                           const float* __restrict__ bn_sum, const float* __restrict__ bn_sq,
                           const float* __restrict__ bn_g, const float* __restrict__ bn_b,
                           int use_bn, const int* __restrict__ cnt,
                           float* sm, int bid, int nwork) {
  float* Ws = sm;
  float* xs = sm + 4096;
  float* bnsc = sm + 8192;
  float* bnsh = sm + 8320;
  int tid = threadIdx.x;
  if (tid < 128) {
    if (use_bn) {
      float s = 0.f, q = 0.f;
      for (int r2 = 0; r2 < NSLOT; ++r2) { s += bn_sum[r2 * 128 + tid]; q += bn_sq[r2 * 128 + tid]; }
      float m = s * invN;
      float var = q * invN - m * m;
      float rs = rsqrtf(var + 1e-5f);
      float sc = rs * bn_g[tid];
      bnsc[tid] = sc;
      bnsh[tid] = bn_b[tid] - m * sc;
    } else {
      bnsc[tid] = 1.f; bnsh[tid] = 0.f;
    }
  }
  int ntiles = (n + 127) >> 7;
  int tx = tid & 15, ty = tid >> 4;
  int c0 = tx * 4, r0 = ty * 4;
  int r = tid & 127;
  int hf = tid >> 7;
  int kw = tid >> 5;
  int c4 = tid & 31;
  for (int tile = bid; tile < ntiles; tile += nwork) {
    int base = tile << 7;
    int row_s = base + r;
    const float4* Arow = (const float4*)(A + (size_t)row_s * 128);
    float acc[8][8];
#pragma unroll
    for (int i = 0; i < 8; ++i)
#pragma unroll
      for (int j = 0; j < 8; ++j) acc[i][j] = 0.f;
    for (int kp = 0; kp < 4; ++kp) {
      __syncthreads();
#pragma unroll
      for (int it = 0; it < 4; ++it) {
        int kl = kw + it * 8;
        float4 wv = ((const float4*)(W + (size_t)(kp * 32 + kl) * 128))[c4];
        *(float4*)&Ws[kl * 128 + c4 * 4] = wv;
      }
#pragma unroll
      for (int it = 0; it < 4; ++it) {
        int kbl = hf + it * 2;
        float4 v = make_float4(0.f, 0.f, 0.f, 0.f);
        if (row_s < n) v = Arow[kp * 8 + kbl];
        if (use_bn) {
          int k0 = kp * 32 + kbl * 4;
          float t;
          t = v.x * bnsc[k0 + 0] + bnsh[k0 + 0]; v.x = t >= 0.f ? t : 0.1f * t;
          t = v.y * bnsc[k0 + 1] + bnsh[k0 + 1]; v.y = t >= 0.f ? t : 0.1f * t;
          t = v.z * bnsc[k0 + 2] + bnsh[k0 + 2]; v.z = t >= 0.f ? t : 0.1f * t;
          t = v.w * bnsc[k0 + 3] + bnsh[k0 + 3]; v.w = t >= 0.f ? t : 0.1f * t;
        }
        int kl = kbl * 4;
        xs[(kl + 0) * 128 + r] = v.x;
        xs[(kl + 1) * 128 + r] = v.y;
        xs[(kl + 2) * 128 + r] = v.z;
        xs[(kl + 3) * 128 + r] = v.w;
      }
      __syncthreads();
#pragma unroll 4
      for (int k = 0; k < 32; ++k) {
        float4 a0 = *(const float4*)&xs[k * 128 + r0];
        float4 a1 = *(const float4*)&xs[k * 128 + 64 + r0];
        float4 w0 = *(const float4*)&Ws[k * 128 + c0];
        float4 w1 = *(const float4*)&Ws[k * 128 + 64 + c0];
        float xr[8], wc[8];
        xr[0] = a0.x; xr[1] = a0.y; xr[2] = a0.z; xr[3] = a0.w;
        xr[4] = a1.x; xr[5] = a1.y; xr[6] = a1.z; xr[7] = a1.w;
        wc[0] = w0.x; wc[1] = w0.y; wc[2] = w0.z; wc[3] = w0.w;
        wc[4] = w1.x; wc[5] = w1.y; wc[6] = w1.z; wc[7] = w1.w;
#pragma unroll
        for (int i = 0; i < 8; ++i)
#pragma unroll
          for (int j = 0; j < 8; ++j)
            acc[i][j] = fmaf(xr[i], wc[j], acc[i][j]);
      }
    }
    float bb0[4], bb1[4];
#pragma unroll
    for (int j = 0; j < 4; ++j) { bb0[j] = bias[c0 + j]; bb1[j] = bias[64 + c0 + j]; }
#pragma unroll
    for (int i = 0; i < 8; ++i) {
      int row = base + (i < 4 ? r0 + i : 64 + r0 + (i - 4));
      if (row < n) {
        float rs = rsqrtf((float)(cnt[row] + 1));
        float4 o0, o1;
        o0.x = (acc[i][0] + bb0[0]) * rs; o0.y = (acc[i][1] + bb0[1]) * rs;
        o0.z = (acc[i][2] + bb0[2]) * rs; o0.w = (acc[i][3] + bb0[3]) * rs;
        o1.x = (acc[i][4] + bb1[0]) * rs; o1.y = (acc[i][5] + bb1[1]) * rs;
        o1.z = (acc[i][6] + bb1[2]) * rs; o1.w = (acc[i][7] + bb1[3]) * rs;
        *(float4*)&out[(size_t)row * 128 + c0] = o0;
        *(float4*)&out[(size_t)row * 128 + 64 + c0] = o1;
      }
    }
  }
}

__device__ void agg_phase(const float* __restrict__ z, const int* __restrict__ cnt,
                          const int* __restrict__ csr, float* __restrict__ out,
                          float* __restrict__ Ssum, float* __restrict__ Ssq,
                          int n, int half, float* sm) {
  float* bs = sm;          // 4*128
  float* bq = sm + 512;    // 4*128
  int tid = threadIdx.x;
  int lane = tid & 63;
  int wv = tid >> 6;
  int gwv = (blockIdx.x * blockDim.x + tid) >> 6;
  int nwv = (gridDim.x * blockDim.x) >> 6;
  const float2* __restrict__ h2 = (const float2*)z;
  float stx = 0.f, sty = 0.f, qtx = 0.f, qty = 0.f;
  for (int w = gwv; w < half; w += nwv) {
    int i0 = w, i1 = w + half;
    bool has1 = (i1 < n);
    unsigned off0 = (unsigned)i0 * 64u + (unsigned)lane;
    unsigned off1 = (unsigned)i1 * 64u + (unsigned)lane;
    float2 self0 = h2[off0];
    float2 self1 = has1 ? h2[off1] : make_float2(0.f, 0.f);
    int c0r = cnt[i0];
    int c1r = has1 ? cnt[i1] : 0;
    float d0 = rsqrtf((float)(c0r + 1));
    float d1 = rsqrtf((float)(c1r + 1));
    int e0 = c0r > PAD ? PAD : c0r;
    int e1 = c1r > PAD ? PAD : c1r;
    const int* __restrict__ lp0 = csr + (size_t)i0 * PAD;
    const int* __restrict__ lp1 = csr + (size_t)i1 * PAD;
    float s0x = self0.x, s0y = self0.y;
    float s1x = self1.x, s1y = self1.y;
    int my0 = (lane < e0) ? lp0[lane] : 0;
    int my1 = (lane < e1) ? lp1[lane] : 0;
    int p0 = 0, p1 = 0;
    while (p0 + 8 <= e0 && p1 + 8 <= e1) {
      float2 v0[8], v1[8];
#pragma unroll
      for (int u = 0; u < 8; ++u) { int s = __shfl(my0, p0 + u, 64); v0[u] = h2[(unsigned)s * 64u + (unsigned)lane]; }
#pragma unroll
      for (int u = 0; u < 8; ++u) { int s = __shfl(my1, p1 + u, 64); v1[u] = h2[(unsigned)s * 64u + (unsigned)lane]; }
#pragma unroll
      for (int u = 0; u < 8; ++u) {
        s0x += v0[u].x; s0y += v0[u].y;
        s1x += v1[u].x; s1y += v1[u].y;
      }
      p0 += 8; p1 += 8;
    }
    for (; p0 + 8 <= e0; p0 += 8) {
      float2 v[8];
#pragma unroll
      for (int u = 0; u < 8; ++u) { int s = __shfl(my0, p0 + u, 64); v[u] = h2[(unsigned)s * 64u + (unsigned)lane]; }
#pragma unroll
      for (int u = 0; u < 8; ++u) { s0x += v[u].x; s0y += v[u].y; }
    }
    for (; p0 + 4 <= e0; p0 += 4) {
      float2 v[4];
#pragma unroll
      for (int u = 0; u < 4; ++u) { int s = __shfl(my0, p0 + u, 64); v[u] = h2[(unsigned)s * 64u + (unsigned)lane]; }
#pragma unroll
      for (int u = 0; u < 4; ++u) { s0x += v[u].x; s0y += v[u].y; }
    }
    for (; p0 < e0; ++p0) {
      int s = __shfl(my0, p0, 64);
      float2 v = h2[(unsigned)s * 64u + (unsigned)lane];
      s0x += v.x; s0y += v.y;
    }
    for (; p1 + 8 <= e1; p1 += 8) {
      float2 v[8];
#pragma unroll
      for (int u = 0; u < 8; ++u) { int s = __shfl(my1, p1 + u, 64); v[u] = h2[(unsigned)s * 64u + (unsigned)lane]; }
#pragma unroll
      for (int u = 0; u < 8; ++u) { s1x += v[u].x; s1y += v[u].y; }
    }
    for (; p1 + 4 <= e1; p1 += 4) {
      float2 v[4];
#pragma unroll
      for (int u = 0; u < 4; ++u) { int s = __shfl(my1, p1 + u, 64); v[u] = h2[(unsigned)s * 64u + (unsigned)lane]; }
#pragma unroll
      for (int u = 0; u < 4; ++u) { s1x += v[u].x; s1y += v[u].y; }
    }
    for (; p1 < e1; ++p1) {
      int s = __shfl(my1, p1, 64);
      float2 v = h2[(unsigned)s * 64u + (unsigned)lane];
      s1x += v.x; s1y += v.y;
    }
    float2 o0; o0.x = d0 * s0x; o0.y = d0 * s0y;
    ((float2*)out)[off0] = o0;
    stx += o0.x; qtx = fmaf(o0.x, o0.x, qtx);
    sty += o0.y; qty = fmaf(o0.y, o0.y, qty);
    if (has1) {
      float2 o1; o1.x = d1 * s1x; o1.y = d1 * s1y;
      ((float2*)out)[off1] = o1;
      stx += o1.x; qtx = fmaf(o1.x, o1.x, qtx);
      sty += o1.y; qty = fmaf(o1.y, o1.y, qty);
    }
  }
  __syncthreads();
  bs[wv * 128 + 2 * lane] = stx;  bs[wv * 128 + 2 * lane + 1] = sty;
  bq[wv * 128 + 2 * lane] = qtx;  bq[wv * 128 + 2 * lane + 1] = qty;
  __syncthreads();
  if (tid < 128) {
    float s = bs[tid] + bs[128 + tid] + bs[256 + tid] + bs[384 + tid];
    float q = bq[tid] + bq[128 + tid] + bq[256 + tid] + bq[384 + tid];
    int slot = ((int)blockIdx.x & (NSLOT - 1)) * 128 + tid;
    atomicAdd(&Ssum[slot], s);
    atomicAdd(&Ssq[slot], q);
  }
}

__device__ void decoder_phase(const float* __restrict__ h, const int* __restrict__ dri,
                              const float* __restrict__ M2,
                              const float* __restrict__ Ssum3, const float* __restrict__ Ssq3,
                              const float* __restrict__ g3, const float* __restrict__ be3,
                              float* __restrict__ out, int np, int n, float invN,
                              float* sm, int gid, int gsz) {
  float* sc = sm;        // 128
  float* sh = sm + 128;  // 128
  int tid = threadIdx.x;
  __syncthreads();
  if (tid < 128) {
    float s = 0.f, q = 0.f;
    for (int r2 = 0; r2 < NSLOT; ++r2) { s += Ssum3[r2 * 128 + tid]; q += Ssq3[r2 * 128 + tid]; }
    float m = s * invN;
    float var = q * invN - m * m;
    float rs = rsqrtf(var + 1e-5f);
    float scv = rs * g3[tid];
    sc[tid] = scv;
    sh[tid] = be3[tid] - m * scv;
  }
  __syncthreads();
  int lane = tid & 63;
  int wvid = gid >> 6;
  int nwv = gsz >> 6;
  for (int k = wvid; k < np; k += nwv) {
    int ia = dri[2 * k] - 1;     if (ia < 0) ia += n;
    int ib = dri[2 * k + 1] - 1; if (ib < 0) ib += n;
    const float2* ap2 = (const float2*)(h + (size_t)ia * 128);
    const float* bp = h + (size_t)ib * 128;
    float2 a2 = ap2[lane];
    float ax = a2.x * sc[2 * lane] + sh[2 * lane];         ax = ax >= 0.f ? ax : 0.1f * ax;
    float ay = a2.y * sc[2 * lane + 1] + sh[2 * lane + 1]; ay = ay >= 0.f ? ay : 0.1f * ay;
    float u0 = 0.f, u1 = 0.f;
#pragma unroll 4
    for (int i2 = 0; i2 < 64; ++i2) {
      float avx = __shfl(ax, i2, 64);
      float avy = __shfl(ay, i2, 64);
      const float* Mr = M2 + (size_t)(2 * i2) * 128;
      u0 = fmaf(avx, Mr[lane], u0);
      u1 = fmaf(avx, Mr[64 + lane], u1);
      u0 = fmaf(avy, Mr[128 + lane], u0);
      u1 = fmaf(avy, Mr[192 + lane], u1);
    }
    float b0 = bp[lane] * sc[lane] + sh[lane];                b0 = b0 >= 0.f ? b0 : 0.1f * b0;
    float b1 = bp[lane + 64] * sc[lane + 64] + sh[lane + 64]; b1 = b1 >= 0.f ? b1 : 0.1f * b1;
    float part = u0 * b0 + u1 * b1;
#pragma unroll
    for (int o = 32; o; o >>= 1) part += __shfl_down(part, o, 64);
    if (lane == 0) out[k] = part;
  }
}

// ================= mega (cooperative) =================

__global__ __launch_bounds__(NTHR, 4) void mega_kernel(
    const float* __restrict__ x, const int* __restrict__ erow, const int* __restrict__ ecol,
    const int* __restrict__ dri,
    const float* __restrict__ w1, const float* __restrict__ b1,
    const float* __restrict__ w2, const float* __restrict__ b2,
    const float* __restrict__ w3, const float* __restrict__ b3,
    const float* __restrict__ g1, const float* __restrict__ be1,
    const float* __restrict__ g2, const float* __restrict__ be2,
    const float* __restrict__ g3, const float* __restrict__ be3,
    const float* __restrict__ p1, const float* __restrict__ p2,
    float* __restrict__ out,
    float* __restrict__ T1, float* __restrict__ T2,
    int* __restrict__ csr, int* __restrict__ cnt, float* __restrict__ stats,
    float* __restrict__ Mtmp, float* __restrict__ M2,
    int n, int ne, int np, float invN) {
  cg::grid_group grid = cg::this_grid();
  __shared__ float sm[SM_FLOATS];
  int tid = threadIdx.x;
  int bid = blockIdx.x;
  int nb = gridDim.x;
  int gid = bid * NTHR + tid;
  int gsz = nb * NTHR;
  int half = (n + 1) / 2;
  int nstat = 6 * NSLOT * 128;
  float* Ssum1 = stats;
  float* Ssq1  = stats + 1 * NSLOT * 128;
  float* Ssum2 = stats + 2 * NSLOT * 128;
  float* Ssq2  = stats + 3 * NSLOT * 128;
  float* Ssum3 = stats + 4 * NSLOT * 128;
  float* Ssq3  = stats + 5 * NSLOT * 128;
  int nwork1 = nb - 128;

  // ---- P0: zero cnt + stats ----
  for (int j = gid; j < n; j += gsz) cnt[j] = 0;
  for (int j = gid; j < nstat; j += gsz) stats[j] = 0.f;
  grid.sync();

  // ---- P1: fillcsr  |  bilinear-A (Mtmp = p1 @ p2) ----
  if (bid < nwork1) {
    for (int e = bid * NTHR + tid; e < ne; e += nwork1 * NTHR) {
      int d = ecol[e];
      int p = atomicAdd(&cnt[d], 1);
      if (p < PAD) csr[d * PAD + p] = erow[e];
    }
  } else {
    int i = bid - nwork1;
    if (tid < 128) sm[tid] = p1[i * 128 + tid];
    __syncthreads();
    if (tid < 128) {
      float a0 = 0.f, a1 = 0.f, a2 = 0.f, a3 = 0.f;
      for (int k = 0; k < 128; k += 4) {
        a0 = fmaf(sm[k + 0], p2[(k + 0) * 128 + tid], a0);
        a1 = fmaf(sm[k + 1], p2[(k + 1) * 128 + tid], a1);
        a2 = fmaf(sm[k + 2], p2[(k + 2) * 128 + tid], a2);
        a3 = fmaf(sm[k + 3], p2[(k + 3) * 128 + tid], a3);
      }
      Mtmp[i * 128 + tid] = (a0 + a1) + (a2 + a3);
    }
  }
  grid.sync();

  // ---- P2: gemm layer1 (no BN)  |  bilinear-B (M2 = Mtmp @ p1^T) ----
  if (bid < nwork1) {
    gemm_phase(x, w1, b1, T1, n, invN, nullptr, nullptr, nullptr, nullptr, 0, cnt, sm, bid, nwork1);
  } else {
    int i = bid - nwork1;
    if (tid < 128) sm[tid] = Mtmp[i * 128 + tid];
    __syncthreads();
    if (tid < 128) {
      const float* pj = p1 + (size_t)tid * 128;
      float a0 = 0.f, a1 = 0.f, a2 = 0.f, a3 = 0.f;
      for (int l = 0; l < 128; l += 4) {
        a0 = fmaf(sm[l + 0], pj[l + 0], a0);
        a1 = fmaf(sm[l + 1], pj[l + 1], a1);
        a2 = fmaf(sm[l + 2], pj[l + 2], a2);
        a3 = fmaf(sm[l + 3], pj[l + 3], a3);
      }
      M2[i * 128 + tid] = (a0 + a1) + (a2 + a3);
    }
  }
  grid.sync();

  // ---- P3: agg1 ----
  agg_phase(T1, cnt, csr, T2, Ssum1, Ssq1, n, half, sm);
  grid.sync();

  // ---- P4: gemm layer2 (BN1) ----
  gemm_phase(T2, w2, b2, T1, n, invN, Ssum1, Ssq1, g1, be1, 1, cnt, sm, bid, nb);
  grid.sync();

  // ---- P5: agg2 ----
  agg_phase(T1, cnt, csr, T2, Ssum2, Ssq2, n, half, sm);
  grid.sync();

  // ---- P6: gemm layer3 (BN2) ----
  gemm_phase(T2, w3, b3, T1, n, invN, Ssum2, Ssq2, g2, be2, 1, cnt, sm, bid, nb);
  grid.sync();

  // ---- P7: agg3 ----
  agg_phase(T1, cnt, csr, T2, Ssum3, Ssq3, n, half, sm);
  grid.sync();

  // ---- P8: decoder ----
  decoder_phase(T2, dri, M2, Ssum3, Ssq3, g3, be3, out, np, n, invN, sm, gid, gsz);
}

// ================= fallback (multi-kernel, R8-equivalent) =================

__global__ void init_kernel(int* __restrict__ cnt, int n) {
  int i = blockIdx.x * blockDim.x + threadIdx.x;
  int stride = gridDim.x * blockDim.x;
  for (int j = i; j < n; j += stride) cnt[j] = 0;
}

__global__ void fillcsr_kernel(const int* __restrict__ row, const int* __restrict__ col,
                               int* __restrict__ cnt, int* __restrict__ csr, int ne,
                               float* __restrict__ stats, int nstat) {
  int gid = blockIdx.x * blockDim.x + threadIdx.x;
  int stride = gridDim.x * blockDim.x;
  for (int j = gid; j < nstat; j += stride) stats[j] = 0.f;
  if (gid < ne) {
    int d = col[gid];
    int p = atomicAdd(&cnt[d], 1);
    if (p < PAD) csr[d * PAD + p] = row[gid];
  }
}

__global__ __launch_bounds__(NTHR, 4) void gemm_kernel(
    const float* __restrict__ A, const float* __restrict__ W, const float* __restrict__ bias,
    float* __restrict__ out, int n, float invN,
    const float* __restrict__ bn_sum, const float* __restrict__ bn_sq,
    const float* __restrict__ bn_g, const float* __restrict__ bn_b, int use_bn,
    const int* __restrict__ cnt) {
  __shared__ float sm[SM_FLOATS];
  gemm_phase(A, W, bias, out, n, invN, bn_sum, bn_sq, bn_g, bn_b, use_bn, cnt, sm, blockIdx.x, gridDim.x);
}

__global__ __launch_bounds__(NTHR) void agg_kernel(const float* __restrict__ z,
                                                   const int* __restrict__ cnt,
                                                   const int* __restrict__ csr,
                                                   float* __restrict__ out,
                                                   float* __restrict__ Ssum,
                                                   float* __restrict__ Ssq,
                                                   int n, int half) {
  __shared__ float sm[1024];
  agg_phase(z, cnt, csr, out, Ssum, Ssq, n, half, sm);
}

__global__ __launch_bounds__(128) void bilinear_m_kernel(const float* __restrict__ p1,
                                                         const float* __restrict__ p2,
                                                         float* __restrict__ M2) {
  __shared__ float Bs[128 * 129];
  __shared__ float rr[128];
  __shared__ float tmp[128];
  int i = blockIdx.x, t = threadIdx.x;
  rr[t] = p1[i * 128 + t];
  const float4* p24 = (const float4*)p2;
#pragma unroll 8
  for (int it = 0; it < 32; ++it) {
    int f4 = t + 128 * it;
    int k = f4 >> 5, c = f4 & 31;
    float4 v = p24[f4];
    float* d = &Bs[k * 129 + c * 4];
    d[0] = v.x; d[1] = v.y; d[2] = v.z; d[3] = v.w;
  }
  __syncthreads();
  float a0 = 0.f;
#pragma unroll 8
  for (int k = 0; k < 128; ++k) a0 = fmaf(rr[k], Bs[k * 129 + t], a0);
  __syncthreads();
  tmp[t] = a0;
  const float4* p14 = (const float4*)p1;
#pragma unroll 8
  for (int it = 0; it < 32; ++it) {
    int f4 = t + 128 * it;
    int k = f4 >> 5, c = f4 & 31;
    float4 v = p14[f4];
    float* d = &Bs[k * 129 + c * 4];
    d[0] = v.x; d[1] = v.y; d[2] = v.z; d[3] = v.w;
  }
  __syncthreads();
  float a1 = 0.f;
#pragma unroll 8
  for (int l = 0; l < 128; ++l) a1 = fmaf(tmp[l], Bs[t * 129 + l], a1);
  M2[i * 128 + t] = a1;
}

__global__ __launch_bounds__(NTHR) void decoder_kernel(
    const float* __restrict__ h, const int* __restrict__ dri, const float* __restrict__ M2,
    const float* __restrict__ Ssum3, const float* __restrict__ Ssq3,
    const float* __restrict__ g3, const float* __restrict__ be3,
    float* __restrict__ out, int np, int n, float invN) {
  __shared__ float sm[256];
  int gid = blockIdx.x * blockDim.x + threadIdx.x;
  int gsz = gridDim.x * blockDim.x;
  decoder_phase(h, dri, M2, Ssum3, Ssq3, g3, be3, out, np, n, invN, sm, gid, gsz);
}

// ================= launcher =================

extern "C" void kernel_launch(void* const* d_in, const int* in_sizes, int n_in,
                              void* d_out, int out_size, void* d_ws, size_t ws_size,
                              hipStream_t stream) {
  const float* x   = (const float*)d_in[0];
  const int*   ei  = (const int*)d_in[1];
  const int*   dri = (const int*)d_in[2];
  const float* w1  = (const float*)d_in[3];
  const float* b1  = (const float*)d_in[4];
  const float* w2  = (const float*)d_in[5];
  const float* b2  = (const float*)d_in[6];
  const float* w3  = (const float*)d_in[7];
  const float* b3  = (const float*)d_in[8];
  const float* g1  = (const float*)d_in[9];
  const float* be1 = (const float*)d_in[10];
  const float* g2  = (const float*)d_in[11];
  const float* be2 = (const float*)d_in[12];
  const float* g3  = (const float*)d_in[13];
  const float* be3 = (const float*)d_in[14];
  const float* p1  = (const float*)d_in[15];
  const float* p2  = (const float*)d_in[16];
  float* out = (float*)d_out;

  int n  = in_sizes[0] / 128;
  int ne = in_sizes[1] / 2;
  int np = in_sizes[2] / 2;
  const int* erow = ei;
  const int* ecol = ei + ne;

  size_t o = 0;
  char* wsb = (char*)d_ws;
  auto alloc = [&](size_t bytes) { void* p = wsb + o; o += (bytes + 255) & ~255ull; return p; };
  float* T1   = (float*)alloc((size_t)n * 128 * 4);
  float* T2   = (float*)alloc((size_t)n * 128 * 4);
  int*   csr  = (int*)alloc((size_t)n * PAD * 4);
  int*   cnt  = (int*)alloc((size_t)n * 4);
  float* stats = (float*)alloc((size_t)(6 * NSLOT * 128) * 4);
  float* Mtmp = (float*)alloc(128 * 128 * 4);
  float* M2   = (float*)alloc(128 * 128 * 4);
  float* Ssum1 = stats;
  float* Ssq1  = stats + 1 * NSLOT * 128;
  float* Ssum2 = stats + 2 * NSLOT * 128;
  float* Ssq2  = stats + 3 * NSLOT * 128;
  float* Ssum3 = stats + 4 * NSLOT * 128;
  float* Ssq3  = stats + 5 * NSLOT * 128;

  float invN = 1.0f / (float)n;

  // ---- cooperative path: size grid from runtime occupancy ----
  int dev = 0;
  hipGetDevice(&dev);
  int nCU = 0;
  hipDeviceGetAttribute(&nCU, hipDeviceAttributeMultiprocessorCount, dev);
  int maxBlocksPerCU = 0;
  hipOccupancyMaxActiveBlocksPerMultiprocessor(&maxBlocksPerCU, mega_kernel, NTHR, 0);
  int nblk = maxBlocksPerCU * nCU;
  if (nblk > 2048) nblk = 2048;

  if (nblk >= 384) {
    void* kargs[] = {
      (void*)&x, (void*)&erow, (void*)&ecol, (void*)&dri,
      (void*)&w1, (void*)&b1, (void*)&w2, (void*)&b2, (void*)&w3, (void*)&b3,
      (void*)&g1, (void*)&be1, (void*)&g2, (void*)&be2, (void*)&g3, (void*)&be3,
      (void*)&p1, (void*)&p2, (void*)&out,
      (void*)&T1, (void*)&T2, (void*)&csr, (void*)&cnt, (void*)&stats,
      (void*)&Mtmp, (void*)&M2,
      (void*)&n, (void*)&ne, (void*)&np, (void*)&invN
    };
    hipError_t err = hipLaunchCooperativeKernel((void*)mega_kernel, dim3(nblk), dim3(NTHR),
                                                kargs, 0, stream);
    if (err == hipSuccess) return;
  }

  // ---- fallback: multi-kernel path (R8-equivalent) ----
  int eb = (ne + 255) / 256;
  int gb = (n + 127) / 128;
  int half = (n + 1) / 2;
  int ab = (half + 3) / 4;
  int nstat = 6 * NSLOT * 128;

  init_kernel<<<256, 256, 0, stream>>>(cnt, n);
  fillcsr_kernel<<<eb, 256, 0, stream>>>(erow, ecol, cnt, csr, ne, stats, nstat);

  gemm_kernel<<<gb, 256, 0, stream>>>(x, w1, b1, T1, n, invN, nullptr, nullptr, nullptr, nullptr, 0, cnt);
  agg_kernel<<<ab, 256, 0, stream>>>(T1, cnt, csr, T2, Ssum1, Ssq1, n, half);

  gemm_kernel<<<gb, 256, 0, stream>>>(T2, w2, b2, T1, n, invN, Ssum1, Ssq1, g1, be1, 1, cnt);
  agg_kernel<<<ab, 256, 0, stream>>>(T1, cnt, csr, T2, Ssum2, Ssq2, n, half);

  gemm_kernel<<<gb, 256, 0, stream>>>(T2, w3, b3, T1, n, invN, Ssum2, Ssq2, g2, be2, 1, cnt);
  agg_kernel<<<ab, 256, 0, stream>>>(T1, cnt, csr, T2, Ssum3, Ssq3, n, half);

  bilinear_m_kernel<<<128, 128, 0, stream>>>(p1, p2, M2);
  decoder_kernel<<<256, 256, 0, stream>>>(T2, dri, M2, Ssum3, Ssq3, g3, be3, out, np, n, invN);
}